// Round 6
// baseline (927.030 us; speedup 1.0000x reference)
//
#include <hip/hip_runtime.h>
#include <hip/hip_bf16.h>

// Performer-style linear attention: B=4, S=8192, H=768, NH=12, HD=64, M=64.
// Round 10: launch-count collapse (10 -> 4 kernels).
//   out[s,c] = sum_{h,m} (qp[b,h,s,m]/(n+eps)) * WKV[b,h,m,c] + bo,
//   WKV[b,h,m,c] = sum_d kv[b,h,m,d] * Wo[h*64+d, c].
// K1 prologue (block-split, all independent): zero | cvt hs->bf16 |
//    fold P into Wq/Wk writing WcatH bf16 B^T-layout DIRECTLY (+bias) |
//    Wv/Wo tile-transposes | bv->biasC.
// K2 gemm_qkv (r5 verbatim): persistent 128x128 -> qp, kpT, vT, ksumF.
// K3 kv_qpn (block-split): 768 kv-accum blocks (MFMA + atomics; last block
//    per bh via device ticket computes WKV[bh] in-kernel) || 6144 qpn blocks
//    (qp <- qp/(n+eps) in place).
// K4 out_gemm (r5 verbatim): out = qpn @ WKVT[b]^T + bo.

#define S_    8192
#define H_    768
#define NH_   12
#define EPS_  1e-6f

typedef unsigned short U16;
typedef short bf16x8 __attribute__((ext_vector_type(8)));
typedef float f32x4  __attribute__((ext_vector_type(4)));

__device__ __forceinline__ U16 f2b(float x) {            // fp32 -> bf16 RNE
  unsigned u = __float_as_uint(x);
  return (U16)((u + 0x7fffu + ((u >> 16) & 1u)) >> 16);
}
__device__ __forceinline__ float b2f(U16 h) {
  return __uint_as_float(((unsigned)h) << 16);
}
__device__ __forceinline__ void gl2lds16(const void* g, void* l) {
  __builtin_amdgcn_global_load_lds(
      (const __attribute__((address_space(1))) void*)g,
      (__attribute__((address_space(3))) void*)l, 16, 0, 0);
}

// ---------- K1: fused prologue ----------
// blocks [0,781): zero kvM+ksumF+tick (199728 floats)
// blocks [781,25357): cvt hs fp32 -> bf16 (24576 blocks)
// blocks [25357,25645): fold_proj_T (288 = 2z * 12h * 12kcB) -> WcatH q|k + bias
// blocks [25645,25789): Wv transpose (144) -> WcatH v part; block 0 copies bv
// blocks [25789,25933): Wo transpose (144) -> WoTH
__global__ __launch_bounds__(256) void prologue(
    const float* __restrict__ hs, const float* __restrict__ Wq,
    const float* __restrict__ bq, const float* __restrict__ Wk,
    const float* __restrict__ bk, const float* __restrict__ Wv,
    const float* __restrict__ bv, const float* __restrict__ Wo,
    const float* __restrict__ P,
    U16* __restrict__ hs_hi, U16* __restrict__ WcatH, U16* __restrict__ WoTH,
    float* __restrict__ biasC, float* __restrict__ zbase) {
  __shared__ float sm[8192];                       // 32 KB, shared by branches
  const int bid = blockIdx.x, tid = threadIdx.x;
  if (bid < 781) {                                 // ---- zero
    int i = bid * 256 + tid;
    if (i < 199728) zbase[i] = 0.f;
    return;
  }
  if (bid < 25357) {                               // ---- cvt (exact 6291456 f4)
    int i = (bid - 781) * 256 + tid;
    float4 x = ((const float4*)hs)[i];
    ushort4 h;
    h.x = f2b(x.x); h.y = f2b(x.y); h.z = f2b(x.z); h.w = f2b(x.w);
    ((ushort4*)hs_hi)[i] = h;
    return;
  }
  if (bid < 25645) {                               // ---- fold_proj_T
    int f = bid - 25357;
    int z = f / 144, rem = f - z * 144, h = rem / 12, kcB = rem - (rem / 12) * 12;
    float* Pl = sm;                                // [64][64]
    float* WL = sm + 4096;                         // [64][64]
    const float* W = z ? Wk : Wq;
    const float4* P4 = (const float4*)(P + (size_t)h * 4096);
#pragma unroll
    for (int p = 0; p < 4; ++p) ((float4*)Pl)[tid + p * 256] = P4[tid + p * 256];
#pragma unroll
    for (int p = 0; p < 4; ++p) {
      int idx = tid + p * 256;
      int kk = idx >> 4, d4 = (idx & 15) * 4;
      *(float4*)&WL[kk * 64 + d4] =
          *(const float4*)&W[(size_t)(kcB * 64 + kk) * H_ + h * 64 + d4];
    }
    __syncthreads();
    const int m = tid & 63, kg = tid >> 6;
    float acc[16] = {};
    for (int d = 0; d < 64; ++d) {
      float pv = Pl[d * 64 + m];
#pragma unroll
      for (int k2 = 0; k2 < 16; ++k2) acc[k2] += WL[(kg * 16 + k2) * 64 + d] * pv;
    }
    U16* dst = WcatH + (size_t)(z * 768 + h * 64 + m) * H_ + kcB * 64 + kg * 16;
#pragma unroll
    for (int k2 = 0; k2 < 16; k2 += 4) {
      ushort4 o;
      o.x = f2b(acc[k2]); o.y = f2b(acc[k2 + 1]);
      o.z = f2b(acc[k2 + 2]); o.w = f2b(acc[k2 + 3]);
      *(ushort4*)&dst[k2] = o;
    }
    if (kcB == 0 && tid < 64) {
      const float* bb = z ? bk : bq;
      float a2 = 0.f;
      for (int d = 0; d < 64; ++d) a2 += bb[h * 64 + d] * Pl[d * 64 + tid];
      biasC[z * 768 + h * 64 + tid] = a2;
    }
    return;
  }
  // ---- Wv / Wo tile transpose
  const int isWo = bid >= 25789;
  int v = bid - (isWo ? 25789 : 25645);
  int kb = v / 12, rb = v - kb * 12;
  const float* W = isWo ? Wo : Wv;
  float (*T)[68] = (float(*)[68])sm;               // 64*68 floats
#pragma unroll
  for (int p = 0; p < 4; ++p) {
    int idx = tid + p * 256;                       // 1024 float4s
    int rr = idx >> 4, c4 = (idx & 15) * 4;
    float4 x = *(const float4*)&W[(size_t)(kb * 64 + rr) * H_ + rb * 64 + c4];
    T[rr][c4] = x.x; T[rr][c4 + 1] = x.y; T[rr][c4 + 2] = x.z; T[rr][c4 + 3] = x.w;
  }
  __syncthreads();
  U16* dst = isWo ? WoTH : WcatH;
  const int rbase = (isWo ? 0 : 1536) + rb * 64;
#pragma unroll
  for (int p = 0; p < 4; ++p) {
    int idx = tid + p * 256;
    int r2 = idx >> 4, c2 = (idx & 15) * 4;
    ushort4 o;
    o.x = f2b(T[c2 + 0][r2]); o.y = f2b(T[c2 + 1][r2]);
    o.z = f2b(T[c2 + 2][r2]); o.w = f2b(T[c2 + 3][r2]);
    *(ushort4*)&dst[(size_t)(rbase + r2) * H_ + kb * 64 + c2] = o;
  }
  if (!isWo && kb == 0 && rb == 0) {               // bv -> biasC[1536..2304)
#pragma unroll
    for (int p = 0; p < 3; ++p) biasC[1536 + tid + p * 256] = bv[tid + p * 256];
  }
}

// ---------- K2: persistent 128x128 bf16 GEMM + fused maxexp epilogue ----------
__global__ __launch_bounds__(256, 2) void gemm_qkv(
    const U16* __restrict__ Ahi, const U16* __restrict__ Bhi,
    const float* __restrict__ bias,
    U16* __restrict__ qp, U16* __restrict__ kpT, U16* __restrict__ vT,
    float* __restrict__ ksumF) {
  __shared__ __align__(16) U16 Us[32768];            // [buf][A/B][128][64] bf16
  const int tid = threadIdx.x, w = tid >> 6, lane = tid & 63;
  const int quad = lane >> 4, l16 = lane & 15;
  const int b = blockIdx.x;                          // 512 persistent blocks
  const int mt = b & 255, nt0 = b >> 8;
  const int rowA0 = mt * 128;
  const int wm = w & 1, wn = w >> 1;
  const U16* srcA[4];
  int rowBl[4];
  unsigned ldsc[4];
  const int kch = ((lane & 7) ^ (lane >> 3)) * 8;    // pre-swizzled src chunk
#pragma unroll
  for (int t = 0; t < 4; ++t) {
    int c = w * 4 + t;
    int row = c * 8 + (lane >> 3);
    srcA[t] = Ahi + (size_t)(rowA0 + row) * H_ + kch;
    rowBl[t] = row;
    ldsc[t] = (unsigned)c * 512;
  }
  auto stage = [&](int jn, int tn, int bi) {
    const int colB = (nt0 + 2 * jn) * 128;
    unsigned ub = (unsigned)bi * 16384u;
#pragma unroll
    for (int t = 0; t < 4; ++t) {
      gl2lds16(srcA[t] + tn * 64, &Us[ub + ldsc[t]]);
      gl2lds16(Bhi + (size_t)(colB + rowBl[t]) * H_ + tn * 64 + kch,
               &Us[ub + 8192u + ldsc[t]]);
    }
  };

  stage(0, 0, 0);
  for (int jj = 0; jj < 9; ++jj) {
    const int colB0 = (nt0 + 2 * jj) * 128;
    f32x4 acc[4][4] = {};
    for (int t = 0; t < 12; ++t) {
      const bool more = !(jj == 8 && t == 11);
      if (more) {
        if (t < 11) stage(jj, t + 1, (t + 1) & 1);
        else        stage(jj + 1, 0, 0);
        asm volatile("s_waitcnt vmcnt(8)" ::: "memory");
      } else {
        asm volatile("s_waitcnt vmcnt(0)" ::: "memory");
      }
      __builtin_amdgcn_sched_barrier(0);
      __builtin_amdgcn_s_barrier();
      __builtin_amdgcn_sched_barrier(0);
      const unsigned ab = (unsigned)(t & 1) * 16384u;
      bf16x8 ah[4][2], bh[4][2];
#pragma unroll
      for (int i = 0; i < 4; ++i)
#pragma unroll
        for (int ks = 0; ks < 2; ++ks)
          ah[i][ks] = *(const bf16x8*)&Us[ab +
              (unsigned)((wm * 64 + i * 16 + l16) * 64 +
                         (((ks * 4 + quad) ^ (l16 & 7)) * 8))];
#pragma unroll
      for (int j = 0; j < 4; ++j)
#pragma unroll
        for (int ks = 0; ks < 2; ++ks)
          bh[j][ks] = *(const bf16x8*)&Us[ab + 8192u +
              (unsigned)((wn * 64 + j * 16 + l16) * 64 +
                         (((ks * 4 + quad) ^ (l16 & 7)) * 8))];
      asm volatile("s_waitcnt lgkmcnt(0)" ::: "memory");
      __builtin_amdgcn_sched_barrier(0);
      __builtin_amdgcn_s_setprio(1);
#pragma unroll
      for (int ks = 0; ks < 2; ++ks)
#pragma unroll
        for (int j = 0; j < 4; ++j)
#pragma unroll
          for (int i = 0; i < 4; ++i)
            acc[i][j] = __builtin_amdgcn_mfma_f32_16x16x32_bf16(
                ah[i][ks], bh[j][ks], acc[i][j], 0, 0, 0);
      __builtin_amdgcn_s_setprio(0);
      __builtin_amdgcn_sched_barrier(0);
      __builtin_amdgcn_s_barrier();
      __builtin_amdgcn_sched_barrier(0);
    }
    // ---- epilogue for this tile (no LDS use; overlaps next stage)
    const int col64 = colB0 + wn * 64;
    float bj[4];
#pragma unroll
    for (int j = 0; j < 4; ++j) bj[j] = bias[col64 + j * 16 + l16];
    if (col64 < 768) {                            // q logits -> row-major qp
      const int h = col64 >> 6;
#pragma unroll
      for (int i = 0; i < 4; ++i) {
#pragma unroll
        for (int r = 0; r < 4; ++r) {
          int row = rowA0 + wm * 64 + i * 16 + quad * 4 + r;
          float v0 = acc[i][0][r] + bj[0], v1 = acc[i][1][r] + bj[1];
          float v2 = acc[i][2][r] + bj[2], v3 = acc[i][3][r] + bj[3];
          float mx = fmaxf(fmaxf(v0, v1), fmaxf(v2, v3));
          mx = fmaxf(mx, __shfl_xor(mx, 1));
          mx = fmaxf(mx, __shfl_xor(mx, 2));
          mx = fmaxf(mx, __shfl_xor(mx, 4));
          mx = fmaxf(mx, __shfl_xor(mx, 8));
          int bb = row >> 13, s = row & 8191;
          size_t base = ((size_t)(bb * NH_ + h) * S_ + s) * 64 + l16;
          qp[base +  0] = f2b(__expf(v0 - mx));
          qp[base + 16] = f2b(__expf(v1 - mx));
          qp[base + 32] = f2b(__expf(v2 - mx));
          qp[base + 48] = f2b(__expf(v3 - mx));
        }
      }
    } else {                                      // k (exp) or v -> transposed
      const int isv = col64 >= 1536;
      const int h = (col64 - (isv ? 1536 : 768)) >> 6;
      U16* dstT = isv ? vT : kpT;
      const int bh2 = (rowA0 >> 13) * NH_ + h;
      float pk[4] = {0.f, 0.f, 0.f, 0.f};
#pragma unroll
      for (int i = 0; i < 4; ++i) {
        float er[4][4];                           // [j][r]
#pragma unroll
        for (int r = 0; r < 4; ++r) {
          float v0 = acc[i][0][r] + bj[0], v1 = acc[i][1][r] + bj[1];
          float v2 = acc[i][2][r] + bj[2], v3 = acc[i][3][r] + bj[3];
          if (!isv) {
            float mx = fmaxf(fmaxf(v0, v1), fmaxf(v2, v3));
            mx = fmaxf(mx, __shfl_xor(mx, 1));
            mx = fmaxf(mx, __shfl_xor(mx, 2));
            mx = fmaxf(mx, __shfl_xor(mx, 4));
            mx = fmaxf(mx, __shfl_xor(mx, 8));
            v0 = __expf(v0 - mx); v1 = __expf(v1 - mx);
            v2 = __expf(v2 - mx); v3 = __expf(v3 - mx);
          }
          er[0][r] = v0; er[1][r] = v1; er[2][r] = v2; er[3][r] = v3;
        }
        if (!isv) {
#pragma unroll
          for (int j = 0; j < 4; ++j)
            pk[j] += er[j][0] + er[j][1] + er[j][2] + er[j][3];
        }
        int n = rowA0 + wm * 64 + i * 16 + quad * 4;   // 4-aligned
        int s = n & 8191;
#pragma unroll
        for (int j = 0; j < 4; ++j) {
          ushort4 o;
          o.x = f2b(er[j][0]); o.y = f2b(er[j][1]);
          o.z = f2b(er[j][2]); o.w = f2b(er[j][3]);
          *(ushort4*)&dstT[((size_t)bh2 * 64 + j * 16 + l16) * S_ + s] = o;
        }
      }
      if (!isv) {                                  // ksum partial (64 rows)
#pragma unroll
        for (int j = 0; j < 4; ++j) {
          pk[j] += __shfl_xor(pk[j], 16);
          pk[j] += __shfl_xor(pk[j], 32);
        }
        if (quad == 0) {
#pragma unroll
          for (int j = 0; j < 4; ++j)
            atomicAdd(&ksumF[bh2 * 64 + j * 16 + l16], pk[j]);
        }
      }
    }
  }
}

// ---------- K3: kv-accum (+ ticketed WKV build) || qpn, block-split ----------
// blocks [0,768): bh = bid>>4, n-chunk = bid&15 (512 n each). MFMA kv into
//   kvM[bh][m][d] via atomics; last block per bh (device ticket) loads kvM
//   and computes WKVT[b][c][h*64+m] = sum_d WoT[c][h*64+d]*kv[m][d].
// blocks [768,6912): qpn: qp <- qp/(qp.ksum+eps) in place.
__global__ __launch_bounds__(256, 2) void kv_qpn(
    const U16* __restrict__ kpT, const U16* __restrict__ vT,
    float* __restrict__ kvM, const float* __restrict__ ksumF,
    unsigned* __restrict__ tick, const U16* __restrict__ WoTH,
    U16* __restrict__ WKVT, U16* __restrict__ qp) {
  __shared__ __align__(16) U16 Us[8192];          // 16 KB
  __shared__ int lastf;
  const int bid = blockIdx.x, tid = threadIdx.x;
  if (bid < 768) {
    const int w = tid >> 6, lane = tid & 63;
    const int quad = lane >> 4, l16 = lane & 15;
    const int bh = bid >> 4;
    const int n0 = (bid & 15) * 512;
    const U16* srcs[4];
    unsigned ldsoff[4];
#pragma unroll
    for (int t = 0; t < 4; ++t) {
      int c = w * 4 + t, buf = c >> 3;            // 0..15; buf 0 = vT, 1 = kpT
      int r = (c & 7) * 8 + (lane >> 3);
      const U16* base = buf ? kpT : vT;
      srcs[t] = base + ((size_t)bh * 64 + r) * S_ + n0 + (lane & 7) * 8;
      ldsoff[t] = buf * 4096 + (c & 7) * 512;
    }
    f32x4 acc[4] = {};
    for (int nc = 0; nc < 512; nc += 64) {
#pragma unroll
      for (int t = 0; t < 4; ++t) gl2lds16(srcs[t] + nc, &Us[ldsoff[t]]);
      __syncthreads();
#pragma unroll
      for (int k0 = 0; k0 < 64; k0 += 32) {
        bf16x8 av = *(const bf16x8*)&Us[(w * 16 + l16) * 64 + k0 + quad * 8];
#pragma unroll
        for (int j = 0; j < 4; ++j) {
          bf16x8 bk = *(const bf16x8*)&Us[4096 + (j * 16 + l16) * 64 + k0 + quad * 8];
          acc[j] = __builtin_amdgcn_mfma_f32_16x16x32_bf16(av, bk, acc[j], 0, 0, 0);
        }
      }
      __syncthreads();
    }
    // acc[j][r]: d = w*16+quad*4+r, m = j*16+l16 -> kvM[bh][m][d]
#pragma unroll
    for (int j = 0; j < 4; ++j)
#pragma unroll
      for (int r = 0; r < 4; ++r)
        atomicAdd(&kvM[((size_t)bh * 64 + j * 16 + l16) * 64 + w * 16 + quad * 4 + r],
                  acc[j][r]);
    __threadfence();
    __syncthreads();
    if (tid == 0) lastf = (atomicAdd(&tick[bh], 1u) == 15u) ? 1 : 0;
    __syncthreads();
    if (!lastf) return;
    __threadfence();
    // ---- WKV build for this bh (hidden under concurrent qpn blocks)
    float* kvL = (float*)Us;                       // [64][64] fp32 = 16 KB
#pragma unroll
    for (int p = 0; p < 16; ++p) {
      int i = tid + p * 256;
      kvL[i] = kvM[(size_t)bh * 4096 + i];
    }
    __syncthreads();
    const int b = bh / NH_, h = bh - b * NH_;
    for (int cc = 0; cc < 3; ++cc) {
      int c = tid + cc * 256;
      const U16* wr = WoTH + (size_t)c * H_ + h * 64;
#pragma unroll
      for (int mc = 0; mc < 4; ++mc) {
        float a16[16] = {};
#pragma unroll
        for (int dg = 0; dg < 4; ++dg) {
          ushort4 w0 = *(const ushort4*)&wr[dg * 16 + 0];
          ushort4 w1 = *(const ushort4*)&wr[dg * 16 + 4];
          ushort4 w2 = *(const ushort4*)&wr[dg * 16 + 8];
          ushort4 w3 = *(const ushort4*)&wr[dg * 16 + 12];
          U16 wv16[16] = {w0.x, w0.y, w0.z, w0.w, w1.x, w1.y, w1.z, w1.w,
                          w2.x, w2.y, w2.z, w2.w, w3.x, w3.y, w3.z, w3.w};
#pragma unroll
          for (int dd = 0; dd < 16; ++dd) {
            float wv = b2f(wv16[dd]);
            int d = dg * 16 + dd;
#pragma unroll
            for (int mm = 0; mm < 16; ++mm)
              a16[mm] += wv * kvL[(mc * 16 + mm) * 64 + d];
          }
        }
        U16* dst = WKVT + (size_t)b * 589824 + (size_t)c * H_ + h * 64 + mc * 16;
#pragma unroll
        for (int mm = 0; mm < 16; mm += 4) {
          ushort4 o;
          o.x = f2b(a16[mm]); o.y = f2b(a16[mm + 1]);
          o.z = f2b(a16[mm + 2]); o.w = f2b(a16[mm + 3]);
          *(ushort4*)&dst[mm] = o;
        }
      }
    }
    return;
  }
  // ---- qpn part
  const int qid = bid - 768;
  const int bh = qid >> 7, s0 = (qid & 127) * 64;
  float* ks = (float*)Us;
  if (tid < 64) ks[tid] = ksumF[bh * 64 + tid];
  __syncthreads();
  const int row = tid >> 2, q = tid & 3;
  size_t src = ((size_t)bh * S_ + s0 + row) * 64 + q * 16;
  bf16x8 x0 = *(const bf16x8*)&qp[src];
  bf16x8 x1 = *(const bf16x8*)&qp[src + 8];
  float f[16];
  float n = 0.f;
#pragma unroll
  for (int e = 0; e < 8; ++e) {
    f[e] = b2f((U16)x0[e]);     n += f[e] * ks[q * 16 + e];
    f[e + 8] = b2f((U16)x1[e]); n += f[e + 8] * ks[q * 16 + 8 + e];
  }
  n += __shfl_xor(n, 1);
  n += __shfl_xor(n, 2);
  const float inv = 1.f / (n + EPS_);
#pragma unroll
  for (int g = 0; g < 4; ++g) {
    ushort4 o;
    o.x = f2b(f[g * 4 + 0] * inv); o.y = f2b(f[g * 4 + 1] * inv);
    o.z = f2b(f[g * 4 + 2] * inv); o.w = f2b(f[g * 4 + 3] * inv);
    *(ushort4*)&qp[src + g * 4] = o;
  }
}

// ---------- K4: out = qpn @ WKVT[b]^T + bo (persistent 128x128, BK=64) -------
__global__ __launch_bounds__(256, 2) void out_gemm(
    const U16* __restrict__ qpn, const U16* __restrict__ WKVT,
    const float* __restrict__ bo, float* __restrict__ out) {
  __shared__ __align__(16) U16 Us[32768];
  const int tid = threadIdx.x, w = tid >> 6, lane = tid & 63;
  const int quad = lane >> 4, l16 = lane & 15;
  const int b = blockIdx.x;                          // 512 persistent blocks
  const int mt = b & 255, nt0 = b >> 8;
  const int rowA0 = mt * 128;
  const int batch = mt >> 6, s0 = (mt & 63) * 128;
  const int bh0 = batch * NH_;
  const int wm = w & 1, wn = w >> 1;
  const int kch = ((lane & 7) ^ (lane >> 3)) * 8;
  int rowc[4];
  unsigned ldsc[4];
#pragma unroll
  for (int t = 0; t < 4; ++t) {
    rowc[t] = (w * 4 + t) * 8 + (lane >> 3);
    ldsc[t] = (unsigned)(w * 4 + t) * 512;
  }
  const U16* wb = WKVT + (size_t)batch * 589824;
  auto stage = [&](int jn, int tn, int bi) {
    const int colB = (nt0 * 3 + jn) * 128;
    unsigned ub = (unsigned)bi * 16384u;
    const U16* abase = qpn + ((size_t)(bh0 + tn) * S_ + s0) * 64 + kch;
    const U16* bbase = wb + (size_t)colB * H_ + tn * 64 + kch;
#pragma unroll
    for (int t = 0; t < 4; ++t) {
      gl2lds16(abase + rowc[t] * 64, &Us[ub + ldsc[t]]);
      gl2lds16(bbase + (size_t)rowc[t] * H_, &Us[ub + 8192u + ldsc[t]]);
    }
  };

  stage(0, 0, 0);
  for (int jj = 0; jj < 3; ++jj) {
    const int colB0 = (nt0 * 3 + jj) * 128;
    f32x4 acc[4][4] = {};
    for (int t = 0; t < 12; ++t) {
      const bool more = !(jj == 2 && t == 11);
      if (more) {
        if (t < 11) stage(jj, t + 1, (t + 1) & 1);
        else        stage(jj + 1, 0, 0);
        asm volatile("s_waitcnt vmcnt(8)" ::: "memory");
      } else {
        asm volatile("s_waitcnt vmcnt(0)" ::: "memory");
      }
      __builtin_amdgcn_sched_barrier(0);
      __builtin_amdgcn_s_barrier();
      __builtin_amdgcn_sched_barrier(0);
      const unsigned ab = (unsigned)(t & 1) * 16384u;
      bf16x8 ah[4][2], bh[4][2];
#pragma unroll
      for (int i = 0; i < 4; ++i)
#pragma unroll
        for (int ks = 0; ks < 2; ++ks)
          ah[i][ks] = *(const bf16x8*)&Us[ab +
              (unsigned)((wm * 64 + i * 16 + l16) * 64 +
                         (((ks * 4 + quad) ^ (l16 & 7)) * 8))];
#pragma unroll
      for (int j = 0; j < 4; ++j)
#pragma unroll
        for (int ks = 0; ks < 2; ++ks)
          bh[j][ks] = *(const bf16x8*)&Us[ab + 8192u +
              (unsigned)((wn * 64 + j * 16 + l16) * 64 +
                         (((ks * 4 + quad) ^ (l16 & 7)) * 8))];
      asm volatile("s_waitcnt lgkmcnt(0)" ::: "memory");
      __builtin_amdgcn_sched_barrier(0);
      __builtin_amdgcn_s_setprio(1);
#pragma unroll
      for (int ks = 0; ks < 2; ++ks)
#pragma unroll
        for (int j = 0; j < 4; ++j)
#pragma unroll
          for (int i = 0; i < 4; ++i)
            acc[i][j] = __builtin_amdgcn_mfma_f32_16x16x32_bf16(
                ah[i][ks], bh[j][ks], acc[i][j], 0, 0, 0);
      __builtin_amdgcn_s_setprio(0);
      __builtin_amdgcn_sched_barrier(0);
      __builtin_amdgcn_s_barrier();
      __builtin_amdgcn_sched_barrier(0);
    }
    // ---- epilogue (no LDS use; overlaps next stage)
#pragma unroll
    for (int i = 0; i < 4; ++i) {
      int row = rowA0 + wm * 64 + i * 16 + quad * 4;
#pragma unroll
      for (int j = 0; j < 4; ++j) {
        int col = colB0 + wn * 64 + j * 16 + l16;
        float bvv = bo[col];
#pragma unroll
        for (int r = 0; r < 4; ++r)
          out[(size_t)(row + r) * H_ + col] = acc[i][j][r] + bvv;
      }
    }
  }
}

extern "C" void kernel_launch(void* const* d_in, const int* in_sizes, int n_in,
                              void* d_out, int out_size, void* d_ws, size_t ws_size,
                              hipStream_t stream) {
  const float* hs = (const float*)d_in[0];
  const float* Wq = (const float*)d_in[1];
  const float* bq = (const float*)d_in[2];
  const float* Wk = (const float*)d_in[3];
  const float* bk = (const float*)d_in[4];
  const float* Wv = (const float*)d_in[5];
  const float* bv = (const float*)d_in[6];
  const float* Wo = (const float*)d_in[7];
  const float* bo = (const float*)d_in[8];
  const float* P  = (const float*)d_in[9];
  float* out = (float*)d_out;

  char* ws = (char*)d_ws;
  size_t off = 0;
  auto alloc = [&](size_t bytes) -> void* {
    void* p = ws + off;
    off = (off + bytes + 255) & ~(size_t)255;
    return p;
  };
  U16*   hs_hi = (U16*)alloc(50331648);     // [32768,768] bf16
  U16*   WcatH = (U16*)alloc(3538944);      // [2304,768] bf16 (B^T layout)
  U16*   WoTH  = (U16*)alloc(1179648);      // [768,768] bf16 (Wo^T)
  float* biasC = (float*)alloc(9216);
  U16*   qp    = (U16*)alloc(50331648);     // [48,8192,64] bf16 row-major
  U16*   kpT   = (U16*)alloc(50331648);     // [48,64,8192] bf16 transposed
  U16*   vT    = (U16*)alloc(50331648);     // [48,64,8192] bf16 transposed
  float* kvM   = (float*)alloc(786432);     // [48,64,64] fp32 (m-major)
  float* ksumF = (float*)alloc(12288);      // [48,64] fp32 (contiguous)
  unsigned* tick = (unsigned*)alloc(192);   // [48] tickets (contiguous)
  U16*   WKVT  = (U16*)alloc(4718592);      // [4][768][768] bf16

  prologue<<<dim3(25933), dim3(256), 0, stream>>>(
      hs, Wq, bq, Wk, bk, Wv, bv, Wo, P, hs_hi, WcatH, WoTH, biasC, kvM);
  gemm_qkv<<<dim3(512), dim3(256), 0, stream>>>(hs_hi, WcatH, biasC, qp, kpT, vT, ksumF);
  kv_qpn<<<dim3(6912), dim3(256), 0, stream>>>(kpT, vT, kvM, ksumF, tick, WoTH, WKVT, qp);
  out_gemm<<<dim3(512), dim3(256), 0, stream>>>(qp, WKVT, bo, out);
}

// Round 7
// 480.912 us; speedup vs baseline: 1.9276x; 1.9276x over previous
//
#include <hip/hip_runtime.h>
#include <hip/hip_bf16.h>

// Performer-style linear attention: B=4, S=8192, H=768, NH=12, HD=64, M=64.
// Round 11: best-of-measured hybrid (revert r6).
//   - gemm_qkv: r3's persistent 128x128/BK64 version (measured 167 us, best).
//   - tail: r2's kv_accum_mfma + ctx_gemm_k + gemm_out (part of best total 496).
//   - build_cat -> build_cat_t (coalesced LDS tile transpose, r4/r5-proven).
// Pipeline:
//   K0 zero kvT[48][80][64]
//   K1 cvt hs -> bf16
//   K2 fold P into Wq/Wk (Wqp = Wq * blockdiag(P)) [fp32]
//   K3 build B^T concat weights [Wqp|Wkp|Wv] + WoT as bf16 (tile transpose), bias
//   K4 gemm_qkv (persistent 128x128) -> qp row-major, kpT/vT transposed
//   K5 kv_accum_mfma -> kvT[bh][d][m] fp32, row 64 = ksum
//   K6 ctx_gemm_k: acc = qp @ [kvT|ksum]^T, ctx = acc/(norm+eps) -> bf16
//   K7 gemm_out (256^2 4-phase, 512 thr): out = ctx @ WoT^T + bo -> fp32

#define S_    8192
#define H_    768
#define NH_   12
#define EPS_  1e-6f

typedef unsigned short U16;
typedef short bf16x8 __attribute__((ext_vector_type(8)));
typedef float f32x4  __attribute__((ext_vector_type(4)));

__device__ __forceinline__ U16 f2b(float x) {            // fp32 -> bf16 RNE
  unsigned u = __float_as_uint(x);
  return (U16)((u + 0x7fffu + ((u >> 16) & 1u)) >> 16);
}
__device__ __forceinline__ float b2f(U16 h) {
  return __uint_as_float(((unsigned)h) << 16);
}
__device__ __forceinline__ void gl2lds16(const void* g, void* l) {
  __builtin_amdgcn_global_load_lds(
      (const __attribute__((address_space(1))) void*)g,
      (__attribute__((address_space(3))) void*)l, 16, 0, 0);
}

// ---------- K0: zero scratch ----------
__global__ void zero_f32(float* __restrict__ p, int n) {
  int i = blockIdx.x * 256 + threadIdx.x;
  if (i < n) p[i] = 0.f;
}

// ---------- K1: fp32 -> bf16 ----------
__global__ void cvt_f32_bf16(const float* __restrict__ src, U16* __restrict__ hi, int n4) {
  int i = blockIdx.x * 256 + threadIdx.x;
  if (i >= n4) return;
  float4 x = ((const float4*)src)[i];
  ushort4 h;
  h.x = f2b(x.x); h.y = f2b(x.y); h.z = f2b(x.z); h.w = f2b(x.w);
  ((ushort4*)hi)[i] = h;
}

// ---------- K2: fold P into Wq / Wk (and biases) ----------
__global__ void fold_proj(const float* __restrict__ Wq, const float* __restrict__ bq,
                          const float* __restrict__ Wk, const float* __restrict__ bk,
                          const float* __restrict__ P,
                          float* __restrict__ Wqp, float* __restrict__ bqp,
                          float* __restrict__ Wkp, float* __restrict__ bkp) {
  __shared__ float Pl[64 * 64];
  __shared__ float WL[4 * 64];
  int h = blockIdx.y, kc = blockIdx.x, tid = threadIdx.x;
  const float* W  = blockIdx.z ? Wk : Wq;
  const float* bb = blockIdx.z ? bk : bq;
  float* Wout = blockIdx.z ? Wkp : Wqp;
  float* bout = blockIdx.z ? bkp : bqp;
  const float4* P4 = (const float4*)(P + (size_t)h * 4096);
#pragma unroll
  for (int i = 0; i < 4; ++i) ((float4*)Pl)[tid + i * 256] = P4[tid + i * 256];
  WL[tid] = W[(size_t)(kc * 4 + (tid >> 6)) * H_ + h * 64 + (tid & 63)];
  __syncthreads();
  int kl = tid >> 6, m = tid & 63;
  float acc = 0.f;
#pragma unroll
  for (int d = 0; d < 64; ++d) acc += WL[kl * 64 + d] * Pl[d * 64 + m];
  Wout[(size_t)(kc * 4 + kl) * H_ + h * 64 + m] = acc;
  if (kc == 0 && tid < 64) {
    float a2 = 0.f;
    for (int d = 0; d < 64; ++d) a2 += bb[h * 64 + d] * Pl[d * 64 + tid];
    bout[h * 64 + tid] = a2;
  }
}

// ---------- K3: coalesced tile-transpose build of bf16 weights ----------
__global__ void build_cat_t(const float* __restrict__ Wqp, const float* __restrict__ Wkp,
                            const float* __restrict__ Wv,  const float* __restrict__ Wo,
                            U16* __restrict__ WcatH, U16* __restrict__ WoTH) {
  __shared__ float T[64][68];
  const int kb = blockIdx.x, rb = blockIdx.y, mat = blockIdx.z;
  const int tid = threadIdx.x;
  const float* W = mat == 0 ? Wqp : (mat == 1 ? Wkp : (mat == 2 ? Wv : Wo));
#pragma unroll
  for (int p = 0; p < 4; ++p) {
    int idx = tid + p * 256;                 // 1024 float4s
    int rr = idx >> 4, c4 = (idx & 15) * 4;
    float4 v = *(const float4*)&W[(size_t)(kb * 64 + rr) * H_ + rb * 64 + c4];
    T[rr][c4] = v.x; T[rr][c4 + 1] = v.y; T[rr][c4 + 2] = v.z; T[rr][c4 + 3] = v.w;
  }
  __syncthreads();
  U16* dst = mat == 3 ? WoTH : WcatH;
  const int rbase = (mat == 3 ? 0 : mat * 768) + rb * 64;
#pragma unroll
  for (int p = 0; p < 4; ++p) {
    int idx = tid + p * 256;                 // 4096 ushort4s
    int r2 = idx >> 4, c2 = (idx & 15) * 4;
    ushort4 o;
    o.x = f2b(T[c2 + 0][r2]); o.y = f2b(T[c2 + 1][r2]);
    o.z = f2b(T[c2 + 2][r2]); o.w = f2b(T[c2 + 3][r2]);
    *(ushort4*)&dst[(size_t)(rbase + r2) * H_ + kb * 64 + c2] = o;
  }
}

__global__ void build_bias(const float* __restrict__ bqp, const float* __restrict__ bkp,
                           const float* __restrict__ bv, float* __restrict__ biasC) {
  int i = blockIdx.x * 256 + threadIdx.x;
  if (i >= 2304) return;
  biasC[i] = i < 768 ? bqp[i] : (i < 1536 ? bkp[i - 768] : bv[i - 1536]);
}

// ---------- K4: persistent 128x128 bf16 GEMM + fused maxexp epilogue ----------
// 512 blocks (2/CU), 256 threads (4 waves, 2x2), BK=64, dbuf 32 KB LDS.
// Block b: mt = b&255 fixed (A panel reused), nt = (b>>8) + 2*jj, jj=0..8.
// Continuous depth-1 vmcnt(8) ledger across tile boundaries.
__global__ __launch_bounds__(256, 2) void gemm_qkv(
    const U16* __restrict__ Ahi, const U16* __restrict__ Bhi,
    const float* __restrict__ bias,
    U16* __restrict__ qp, U16* __restrict__ kpT, U16* __restrict__ vT) {
  __shared__ __align__(16) U16 Us[32768];            // [buf][A/B][128][64] bf16
  const int tid = threadIdx.x, w = tid >> 6, lane = tid & 63;
  const int quad = lane >> 4, l16 = lane & 15;
  const int b = blockIdx.x;                          // 512 persistent blocks
  const int mt = b & 255, nt0 = b >> 8;
  const int rowA0 = mt * 128;
  const int wm = w & 1, wn = w >> 1;
  const U16* srcA[4];
  int rowBl[4];
  unsigned ldsc[4];
  const int kch = ((lane & 7) ^ (lane >> 3)) * 8;    // pre-swizzled src chunk
#pragma unroll
  for (int t = 0; t < 4; ++t) {
    int c = w * 4 + t;
    int row = c * 8 + (lane >> 3);
    srcA[t] = Ahi + (size_t)(rowA0 + row) * H_ + kch;
    rowBl[t] = row;
    ldsc[t] = (unsigned)c * 512;
  }
  auto stage = [&](int jn, int tn, int bi) {
    const int colB = (nt0 + 2 * jn) * 128;
    unsigned ub = (unsigned)bi * 16384u;
#pragma unroll
    for (int t = 0; t < 4; ++t) {
      gl2lds16(srcA[t] + tn * 64, &Us[ub + ldsc[t]]);
      gl2lds16(Bhi + (size_t)(colB + rowBl[t]) * H_ + tn * 64 + kch,
               &Us[ub + 8192u + ldsc[t]]);
    }
  };

  stage(0, 0, 0);
  for (int jj = 0; jj < 9; ++jj) {
    const int colB0 = (nt0 + 2 * jj) * 128;
    f32x4 acc[4][4] = {};
    for (int t = 0; t < 12; ++t) {
      const bool more = !(jj == 8 && t == 11);
      if (more) {
        if (t < 11) stage(jj, t + 1, (t + 1) & 1);
        else        stage(jj + 1, 0, 0);
        asm volatile("s_waitcnt vmcnt(8)" ::: "memory");
      } else {
        asm volatile("s_waitcnt vmcnt(0)" ::: "memory");
      }
      __builtin_amdgcn_sched_barrier(0);
      __builtin_amdgcn_s_barrier();
      __builtin_amdgcn_sched_barrier(0);
      const unsigned ab = (unsigned)(t & 1) * 16384u;
      bf16x8 ah[4][2], bh[4][2];
#pragma unroll
      for (int i = 0; i < 4; ++i)
#pragma unroll
        for (int ks = 0; ks < 2; ++ks)
          ah[i][ks] = *(const bf16x8*)&Us[ab +
              (unsigned)((wm * 64 + i * 16 + l16) * 64 +
                         (((ks * 4 + quad) ^ (l16 & 7)) * 8))];
#pragma unroll
      for (int j = 0; j < 4; ++j)
#pragma unroll
        for (int ks = 0; ks < 2; ++ks)
          bh[j][ks] = *(const bf16x8*)&Us[ab + 8192u +
              (unsigned)((wn * 64 + j * 16 + l16) * 64 +
                         (((ks * 4 + quad) ^ (l16 & 7)) * 8))];
      asm volatile("s_waitcnt lgkmcnt(0)" ::: "memory");
      __builtin_amdgcn_sched_barrier(0);
      __builtin_amdgcn_s_setprio(1);
#pragma unroll
      for (int ks = 0; ks < 2; ++ks)
#pragma unroll
        for (int j = 0; j < 4; ++j)
#pragma unroll
          for (int i = 0; i < 4; ++i)
            acc[i][j] = __builtin_amdgcn_mfma_f32_16x16x32_bf16(
                ah[i][ks], bh[j][ks], acc[i][j], 0, 0, 0);
      __builtin_amdgcn_s_setprio(0);
      __builtin_amdgcn_sched_barrier(0);
      __builtin_amdgcn_s_barrier();
      __builtin_amdgcn_sched_barrier(0);
    }
    // ---- epilogue for this tile (no LDS use; overlaps next stage)
    const int col64 = colB0 + wn * 64;
    float bj[4];
#pragma unroll
    for (int j = 0; j < 4; ++j) bj[j] = bias[col64 + j * 16 + l16];
    if (col64 < 768) {                            // q logits -> row-major qp
      const int h = col64 >> 6;
#pragma unroll
      for (int i = 0; i < 4; ++i) {
#pragma unroll
        for (int r = 0; r < 4; ++r) {
          int row = rowA0 + wm * 64 + i * 16 + quad * 4 + r;
          float v0 = acc[i][0][r] + bj[0], v1 = acc[i][1][r] + bj[1];
          float v2 = acc[i][2][r] + bj[2], v3 = acc[i][3][r] + bj[3];
          float mx = fmaxf(fmaxf(v0, v1), fmaxf(v2, v3));
          mx = fmaxf(mx, __shfl_xor(mx, 1));
          mx = fmaxf(mx, __shfl_xor(mx, 2));
          mx = fmaxf(mx, __shfl_xor(mx, 4));
          mx = fmaxf(mx, __shfl_xor(mx, 8));
          int bb = row >> 13, s = row & 8191;
          size_t base = ((size_t)(bb * NH_ + h) * S_ + s) * 64 + l16;
          qp[base +  0] = f2b(__expf(v0 - mx));
          qp[base + 16] = f2b(__expf(v1 - mx));
          qp[base + 32] = f2b(__expf(v2 - mx));
          qp[base + 48] = f2b(__expf(v3 - mx));
        }
      }
    } else {                                      // k (exp) or v -> transposed
      const int isv = col64 >= 1536;
      const int h = (col64 - (isv ? 1536 : 768)) >> 6;
      U16* dstT = isv ? vT : kpT;
      const int bh2 = (rowA0 >> 13) * NH_ + h;
#pragma unroll
      for (int i = 0; i < 4; ++i) {
        float er[4][4];                           // [j][r]
#pragma unroll
        for (int r = 0; r < 4; ++r) {
          float v0 = acc[i][0][r] + bj[0], v1 = acc[i][1][r] + bj[1];
          float v2 = acc[i][2][r] + bj[2], v3 = acc[i][3][r] + bj[3];
          if (!isv) {
            float mx = fmaxf(fmaxf(v0, v1), fmaxf(v2, v3));
            mx = fmaxf(mx, __shfl_xor(mx, 1));
            mx = fmaxf(mx, __shfl_xor(mx, 2));
            mx = fmaxf(mx, __shfl_xor(mx, 4));
            mx = fmaxf(mx, __shfl_xor(mx, 8));
            v0 = __expf(v0 - mx); v1 = __expf(v1 - mx);
            v2 = __expf(v2 - mx); v3 = __expf(v3 - mx);
          }
          er[0][r] = v0; er[1][r] = v1; er[2][r] = v2; er[3][r] = v3;
        }
        int n = rowA0 + wm * 64 + i * 16 + quad * 4;   // 4-aligned
        int s = n & 8191;
#pragma unroll
        for (int j = 0; j < 4; ++j) {
          ushort4 o;
          o.x = f2b(er[j][0]); o.y = f2b(er[j][1]);
          o.z = f2b(er[j][2]); o.w = f2b(er[j][3]);
          *(ushort4*)&dstT[((size_t)bh2 * 64 + j * 16 + l16) * S_ + s] = o;
        }
      }
    }
  }
}

// ---------- K5: kv summary via MFMA: kvT[bh][d][m], row 64 = ksum ----------
// grid (16, 48). A-role = vT rows (d), B-role = kpT rows (m), K = n (512/block).
__global__ __launch_bounds__(256, 4) void kv_accum_mfma(
    const U16* __restrict__ kpT, const U16* __restrict__ vT,
    float* __restrict__ kvT) {
  __shared__ __align__(16) U16 Us[2 * 64 * 64];   // [0:4096]=vT tile, [4096:8192]=kpT
  const int tid = threadIdx.x, w = tid >> 6, lane = tid & 63;
  const int quad = lane >> 4, l16 = lane & 15;
  const int bh = blockIdx.y;
  const int n0 = blockIdx.x * 512;
  const U16* srcs[4];
  unsigned ldsoff[4];
#pragma unroll
  for (int t = 0; t < 4; ++t) {
    int c = w * 4 + t, buf = c >> 3;              // 0..15; buf 0 = vT, 1 = kpT
    int r = (c & 7) * 8 + (lane >> 3);
    const U16* base = buf ? kpT : vT;
    srcs[t] = base + ((size_t)bh * 64 + r) * S_ + n0 + (lane & 7) * 8;
    ldsoff[t] = buf * 4096 + (c & 7) * 512;
  }
  f32x4 acc[4] = {};
  float ks[4] = {0.f, 0.f, 0.f, 0.f};
  for (int nc = 0; nc < 512; nc += 64) {
#pragma unroll
    for (int t = 0; t < 4; ++t) gl2lds16(srcs[t] + nc, &Us[ldsoff[t]]);
    __syncthreads();
#pragma unroll
    for (int k0 = 0; k0 < 64; k0 += 32) {
      bf16x8 av = *(const bf16x8*)&Us[(w * 16 + l16) * 64 + k0 + quad * 8];
#pragma unroll
      for (int j = 0; j < 4; ++j) {
        bf16x8 bk = *(const bf16x8*)&Us[4096 + (j * 16 + l16) * 64 + k0 + quad * 8];
        if (w == 0) {
#pragma unroll
          for (int e = 0; e < 8; ++e) ks[j] += b2f((U16)bk[e]);
        }
        acc[j] = __builtin_amdgcn_mfma_f32_16x16x32_bf16(av, bk, acc[j], 0, 0, 0);
      }
    }
    __syncthreads();
  }
#pragma unroll
  for (int j = 0; j < 4; ++j)
#pragma unroll
    for (int r = 0; r < 4; ++r) {
      int d = w * 16 + quad * 4 + r;
      atomicAdd(&kvT[((size_t)bh * 80 + d) * 64 + j * 16 + l16], acc[j][r]);
    }
  if (w == 0) {
#pragma unroll
    for (int j = 0; j < 4; ++j) {
      ks[j] += __shfl_xor(ks[j], 16);
      ks[j] += __shfl_xor(ks[j], 32);
    }
    if (lane < 16) {
#pragma unroll
      for (int j = 0; j < 4; ++j)
        atomicAdd(&kvT[((size_t)bh * 80 + 64) * 64 + j * 16 + lane], ks[j]);
    }
  }
}

// ---------- K6: ctx = (qp @ kv)/(norm+eps); norm = MFMA tile j=4 ----------
__global__ __launch_bounds__(256) void ctx_gemm_k(
    const U16* __restrict__ qp, const float* __restrict__ kvT,
    U16* __restrict__ ctx) {
  __shared__ __align__(16) U16 As[128 * 64];
  __shared__ __align__(16) U16 Bs[80 * 64];
  int bh = blockIdx.y, row0 = blockIdx.x * 128;
  int tid = threadIdx.x, w = tid >> 6, lane = tid & 63;
  int quad = lane >> 4, l16 = lane & 15;
  const U16* Ab = qp + ((size_t)bh * S_ + row0) * 64;
#pragma unroll
  for (int t = 0; t < 4; ++t) {
    int cb = (w * 4 + t) * 64;
    gl2lds16(Ab + (size_t)(cb + lane) * 8, &As[cb * 8]);
  }
  const float4* kv4 = (const float4*)(kvT + (size_t)bh * 5120);
#pragma unroll
  for (int t = 0; t < 5; ++t) {
    int idx = t * 256 + tid;          // 1280 float4s = 80*64 floats
    float4 f = kv4[idx];
    ushort4 o;
    o.x = f2b(f.x); o.y = f2b(f.y); o.z = f2b(f.z); o.w = f2b(f.w);
    *(ushort4*)&Bs[idx * 4] = o;
  }
  __syncthreads();
  f32x4 acc[2][5] = {};
#pragma unroll
  for (int k0 = 0; k0 < 64; k0 += 32) {
    bf16x8 a[2], fb[5];
#pragma unroll
    for (int i = 0; i < 2; ++i)
      a[i] = *(const bf16x8*)&As[(w * 32 + i * 16 + l16) * 64 + k0 + quad * 8];
#pragma unroll
    for (int j = 0; j < 5; ++j)
      fb[j] = *(const bf16x8*)&Bs[(j * 16 + l16) * 64 + k0 + quad * 8];
#pragma unroll
    for (int j = 0; j < 5; ++j)
#pragma unroll
      for (int i = 0; i < 2; ++i)
        acc[i][j] = __builtin_amdgcn_mfma_f32_16x16x32_bf16(a[i], fb[j], acc[i][j], 0, 0, 0);
  }
  int b = bh / NH_, h = bh - b * NH_;
#pragma unroll
  for (int i = 0; i < 2; ++i) {
#pragma unroll
    for (int r = 0; r < 4; ++r) {
      int s = row0 + w * 32 + i * 16 + quad * 4 + r;
      float nv = __shfl(acc[i][4][r], lane & 48);   // col 64 (l16==0) = norm(row)
      float inv = 1.f / (nv + EPS_);
      size_t base = ((size_t)b * S_ + s) * H_ + h * 64;
#pragma unroll
      for (int j = 0; j < 4; ++j)
        ctx[base + j * 16 + l16] = f2b(acc[i][j][r] * inv);
    }
  }
}

// ---- shared GEMM K-loop macro (r2): 256x256 tile, BK=64, 8 waves (2m x 4n),
// per-wave 128x64 output, dbuf LDS, 4-phase schedule.
#define GEMM_KLOOP()                                                         \
  auto stage = [&](int kt, int bi) {                                         \
    const U16* ap = As + kt * 64;                                            \
    const U16* bp = Bs + kt * 64;                                            \
    unsigned ub = (unsigned)bi * 32768u + lb;                                \
    _Pragma("unroll")                                                        \
    for (int q = 0; q < 4; ++q) {                                            \
      gl2lds16(ap + (size_t)(q * 64) * H_, &Us[ub + q * 4096]);              \
      gl2lds16(bp + (size_t)(q * 64) * H_, &Us[ub + 16384u + q * 4096]);     \
    }                                                                        \
  };                                                                         \
  auto swzo = [&](int ks) { return (((ks * 4 + quad) ^ (l16 & 7)) * 8); };   \
  stage(0, 0);                                                               \
  for (int t = 0; t < 12; ++t) {                                             \
    const unsigned ab = (unsigned)(t & 1) * 32768u;                          \
    if (t < 11) {                                                            \
      stage(t + 1, (t + 1) & 1);                                             \
      asm volatile("s_waitcnt vmcnt(8)" ::: "memory");                       \
    } else {                                                                 \
      asm volatile("s_waitcnt vmcnt(0)" ::: "memory");                       \
    }                                                                        \
    __builtin_amdgcn_sched_barrier(0);                                       \
    __builtin_amdgcn_s_barrier();                                            \
    __builtin_amdgcn_sched_barrier(0);                                       \
    bf16x8 ah[8], bh[4];                                                     \
    _Pragma("unroll")                                                        \
    for (int i = 0; i < 4; ++i)                                              \
      _Pragma("unroll")                                                      \
      for (int ks = 0; ks < 2; ++ks)                                         \
        ah[i * 2 + ks] = *(const bf16x8*)&Us[ab +                            \
            (unsigned)((wm * 128 + i * 16 + l16) * 64 + swzo(ks))];          \
    _Pragma("unroll")                                                        \
    for (int jj = 0; jj < 2; ++jj)                                           \
      _Pragma("unroll")                                                      \
      for (int ks = 0; ks < 2; ++ks)                                         \
        bh[jj * 2 + ks] = *(const bf16x8*)&Us[ab + 16384u +                  \
            (unsigned)((wn * 64 + jj * 16 + l16) * 64 + swzo(ks))];          \
    PHASE_TAIL(0, 0)                                                         \
    _Pragma("unroll")                                                        \
    for (int jj = 0; jj < 2; ++jj)                                           \
      _Pragma("unroll")                                                      \
      for (int ks = 0; ks < 2; ++ks)                                         \
        bh[jj * 2 + ks] = *(const bf16x8*)&Us[ab + 16384u +                  \
            (unsigned)((wn * 64 + (2 + jj) * 16 + l16) * 64 + swzo(ks))];    \
    PHASE_TAIL(0, 1)                                                         \
    _Pragma("unroll")                                                        \
    for (int i = 0; i < 4; ++i)                                              \
      _Pragma("unroll")                                                      \
      for (int ks = 0; ks < 2; ++ks)                                         \
        ah[i * 2 + ks] = *(const bf16x8*)&Us[ab +                            \
            (unsigned)((wm * 128 + 64 + i * 16 + l16) * 64 + swzo(ks))];     \
    PHASE_TAIL(1, 1)                                                         \
    _Pragma("unroll")                                                        \
    for (int jj = 0; jj < 2; ++jj)                                           \
      _Pragma("unroll")                                                      \
      for (int ks = 0; ks < 2; ++ks)                                         \
        bh[jj * 2 + ks] = *(const bf16x8*)&Us[ab + 16384u +                  \
            (unsigned)((wn * 64 + jj * 16 + l16) * 64 + swzo(ks))];          \
    PHASE_TAIL(1, 0)                                                         \
  }

#define PHASE_TAIL(mh, jh)                                                   \
    __builtin_amdgcn_sched_barrier(0);                                       \
    __builtin_amdgcn_s_barrier();                                            \
    asm volatile("s_waitcnt lgkmcnt(0)" ::: "memory");                       \
    __builtin_amdgcn_sched_barrier(0);                                       \
    __builtin_amdgcn_s_setprio(1);                                           \
    _Pragma("unroll")                                                        \
    for (int jj = 0; jj < 2; ++jj)                                           \
      _Pragma("unroll")                                                      \
      for (int i = 0; i < 4; ++i)                                            \
        _Pragma("unroll")                                                    \
        for (int ks = 0; ks < 2; ++ks)                                       \
          acc[(mh) * 4 + i][(jh) * 2 + jj] =                                 \
              __builtin_amdgcn_mfma_f32_16x16x32_bf16(                       \
                  ah[i * 2 + ks], bh[jj * 2 + ks],                           \
                  acc[(mh) * 4 + i][(jh) * 2 + jj], 0, 0, 0);                \
    __builtin_amdgcn_s_setprio(0);                                           \
    __builtin_amdgcn_sched_barrier(0);                                       \
    __builtin_amdgcn_s_barrier();                                            \
    __builtin_amdgcn_sched_barrier(0);

// ---------- K7: pipelined 256^2 bf16 GEMM (output projection) ----------
__global__ __launch_bounds__(512, 2) void gemm_out(
    const U16* __restrict__ Ahi, const U16* __restrict__ Bhi,
    const float* __restrict__ bias, float* __restrict__ C) {
  __shared__ __align__(16) U16 Us[65536];
  const int tid = threadIdx.x, w = tid >> 6, lane = tid & 63;
  const int quad = lane >> 4, l16 = lane & 15;
  const int id = blockIdx.x;
  // 384 = 8 XCD * (16 mt * 3 nt), mt stripes per XCD, nt fastest
  const int xcd = id & 7, pos = id >> 3;
  const int mt = xcd * 16 + pos / 3, nt = pos % 3;
  const int rowA0 = mt * 256, colB0 = nt * 256;
  const int wm = w >> 2, wn = w & 3;
  const int srow = w * 8 + (lane >> 3);
  const int kch = ((lane & 7) ^ (lane >> 3)) * 8;
  const U16* As = Ahi + (size_t)(rowA0 + srow) * H_ + kch;
  const U16* Bs = Bhi + (size_t)(colB0 + srow) * H_ + kch;
  const unsigned lb = (unsigned)(w * 8) * 64;

  f32x4 acc[8][4] = {};
  GEMM_KLOOP()

#pragma unroll
  for (int f = 0; f < 8; ++f) {
    int row = rowA0 + wm * 128 + f * 16 + quad * 4;
#pragma unroll
    for (int j = 0; j < 4; ++j) {
      int col = colB0 + wn * 64 + j * 16 + l16;
      float bvv = bias[col];
#pragma unroll
      for (int r = 0; r < 4; ++r)
        C[(size_t)(row + r) * H_ + col] = acc[f][j][r] + bvv;
    }
  }
}

extern "C" void kernel_launch(void* const* d_in, const int* in_sizes, int n_in,
                              void* d_out, int out_size, void* d_ws, size_t ws_size,
                              hipStream_t stream) {
  const float* hs = (const float*)d_in[0];
  const float* Wq = (const float*)d_in[1];
  const float* bq = (const float*)d_in[2];
  const float* Wk = (const float*)d_in[3];
  const float* bk = (const float*)d_in[4];
  const float* Wv = (const float*)d_in[5];
  const float* bv = (const float*)d_in[6];
  const float* Wo = (const float*)d_in[7];
  const float* bo = (const float*)d_in[8];
  const float* P  = (const float*)d_in[9];
  float* out = (float*)d_out;

  char* ws = (char*)d_ws;
  size_t off = 0;
  auto alloc = [&](size_t bytes) -> void* {
    void* p = ws + off;
    off = (off + bytes + 255) & ~(size_t)255;
    return p;
  };
  U16*   hs_hi = (U16*)alloc(50331648);     // [32768,768] bf16 (reused as ctx)
  float* WqpF  = (float*)alloc(2359296);
  float* WkpF  = (float*)alloc(2359296);
  float* bqpF  = (float*)alloc(3072);
  float* bkpF  = (float*)alloc(3072);
  U16*   WcatH = (U16*)alloc(3538944);      // [2304,768] bf16
  U16*   WoTH  = (U16*)alloc(1179648);
  float* biasC = (float*)alloc(9216);
  U16*   qp    = (U16*)alloc(50331648);     // [48,8192,64] bf16 row-major
  U16*   kpT   = (U16*)alloc(50331648);     // [48,64,8192] bf16 transposed
  U16*   vT    = (U16*)alloc(50331648);     // [48,64,8192] bf16 transposed
  float* kvT   = (float*)alloc(983040);     // [48,80,64] fp32 (row 64 = ksum)
  U16*   ctx   = hs_hi;                     // hs dead after QKV GEMM: reuse

  zero_f32<<<dim3(960), dim3(256), 0, stream>>>(kvT, 245760);
  cvt_f32_bf16<<<dim3(24576), dim3(256), 0, stream>>>(hs, hs_hi, 6291456);
  fold_proj<<<dim3(192, 12, 2), dim3(256), 0, stream>>>(Wq, bq, Wk, bk, P, WqpF, bqpF, WkpF, bkpF);
  build_cat_t<<<dim3(12, 12, 4), dim3(256), 0, stream>>>(WqpF, WkpF, Wv, Wo, WcatH, WoTH);
  build_bias<<<dim3(9), dim3(256), 0, stream>>>(bqpF, bkpF, bv, biasC);
  gemm_qkv<<<dim3(512), dim3(256), 0, stream>>>(hs_hi, WcatH, biasC, qp, kpT, vT);
  kv_accum_mfma<<<dim3(16, 48), dim3(256), 0, stream>>>(kpT, vT, kvT);
  ctx_gemm_k<<<dim3(64, 48), dim3(256), 0, stream>>>(qp, kvT, ctx);
  gemm_out<<<dim3(384), dim3(512), 0, stream>>>(ctx, WoTH, bo, out);
}

// Round 8
// 461.471 us; speedup vs baseline: 2.0089x; 1.0421x over previous
//
#include <hip/hip_runtime.h>
#include <hip/hip_bf16.h>

// Performer-style linear attention: B=4, S=8192, H=768, NH=12, HD=64, M=64.
// Round 12: r7 hybrid + two measured-component upgrades.
//   - prologue: r6's block-split mega-kernel (zero | cvt | fold-P->WcatH bf16
//     direct | Wv/Wo tile-transpose | bias), one launch instead of five.
//   - gemm_out: persistent 128x128/BK64 clone of gemm_qkv's loop (2 blocks/CU,
//     512 blocks, 3-tile nt sweep) replacing the 384-block 256^2 version.
//   - gemm_qkv / kv_accum_mfma / ctx_gemm_k: r7 verbatim.
// Pipeline:
//   K1 prologue -> hs_hi bf16, WcatH, WoTH, biasC, kvT zeroed
//   K2 gemm_qkv (persistent 128x128) -> qp row-major, kpT/vT transposed
//   K3 kv_accum_mfma -> kvT[bh][d][m] fp32, row 64 = ksum
//   K4 ctx_gemm_k: acc = qp @ [kvT|ksum]^T, ctx = acc/(norm+eps) -> bf16
//   K5 out_gemm (persistent 128x128): out = ctx @ WoT^T + bo -> fp32

#define S_    8192
#define H_    768
#define NH_   12
#define EPS_  1e-6f

typedef unsigned short U16;
typedef short bf16x8 __attribute__((ext_vector_type(8)));
typedef float f32x4  __attribute__((ext_vector_type(4)));

__device__ __forceinline__ U16 f2b(float x) {            // fp32 -> bf16 RNE
  unsigned u = __float_as_uint(x);
  return (U16)((u + 0x7fffu + ((u >> 16) & 1u)) >> 16);
}
__device__ __forceinline__ float b2f(U16 h) {
  return __uint_as_float(((unsigned)h) << 16);
}
__device__ __forceinline__ void gl2lds16(const void* g, void* l) {
  __builtin_amdgcn_global_load_lds(
      (const __attribute__((address_space(1))) void*)g,
      (__attribute__((address_space(3))) void*)l, 16, 0, 0);
}

// ---------- K1: fused prologue (all branches independent) ----------
// blocks [0,960): zero kvT (245760 floats)
// blocks [960,25536): cvt hs fp32 -> bf16 (24576 blocks, exact)
// blocks [25536,25824): fold_proj_T (288 = 2z * 12h * 12kcB) -> WcatH q|k + bias
// blocks [25824,25968): Wv transpose (144) -> WcatH v part; block 0 copies bv
// blocks [25968,26112): Wo transpose (144) -> WoTH
__global__ __launch_bounds__(256) void prologue(
    const float* __restrict__ hs, const float* __restrict__ Wq,
    const float* __restrict__ bq, const float* __restrict__ Wk,
    const float* __restrict__ bk, const float* __restrict__ Wv,
    const float* __restrict__ bv, const float* __restrict__ Wo,
    const float* __restrict__ P,
    U16* __restrict__ hs_hi, U16* __restrict__ WcatH, U16* __restrict__ WoTH,
    float* __restrict__ biasC, float* __restrict__ zbase) {
  __shared__ float sm[8192];                       // 32 KB, shared by branches
  const int bid = blockIdx.x, tid = threadIdx.x;
  if (bid < 960) {                                 // ---- zero kvT
    zbase[bid * 256 + tid] = 0.f;
    return;
  }
  if (bid < 25536) {                               // ---- cvt (exact 6291456 f4)
    int i = (bid - 960) * 256 + tid;
    float4 x = ((const float4*)hs)[i];
    ushort4 h;
    h.x = f2b(x.x); h.y = f2b(x.y); h.z = f2b(x.z); h.w = f2b(x.w);
    ((ushort4*)hs_hi)[i] = h;
    return;
  }
  if (bid < 25824) {                               // ---- fold_proj_T
    int f = bid - 25536;
    int z = f / 144, rem = f - z * 144, h = rem / 12, kcB = rem - (rem / 12) * 12;
    float* Pl = sm;                                // [64][64]
    float* WL = sm + 4096;                         // [64][64]
    const float* W = z ? Wk : Wq;
    const float4* P4 = (const float4*)(P + (size_t)h * 4096);
#pragma unroll
    for (int p = 0; p < 4; ++p) ((float4*)Pl)[tid + p * 256] = P4[tid + p * 256];
#pragma unroll
    for (int p = 0; p < 4; ++p) {
      int idx = tid + p * 256;
      int kk = idx >> 4, d4 = (idx & 15) * 4;
      *(float4*)&WL[kk * 64 + d4] =
          *(const float4*)&W[(size_t)(kcB * 64 + kk) * H_ + h * 64 + d4];
    }
    __syncthreads();
    const int m = tid & 63, kg = tid >> 6;
    float acc[16] = {};
    for (int d = 0; d < 64; ++d) {
      float pv = Pl[d * 64 + m];
#pragma unroll
      for (int k2 = 0; k2 < 16; ++k2) acc[k2] += WL[(kg * 16 + k2) * 64 + d] * pv;
    }
    U16* dst = WcatH + (size_t)(z * 768 + h * 64 + m) * H_ + kcB * 64 + kg * 16;
#pragma unroll
    for (int k2 = 0; k2 < 16; k2 += 4) {
      ushort4 o;
      o.x = f2b(acc[k2]); o.y = f2b(acc[k2 + 1]);
      o.z = f2b(acc[k2 + 2]); o.w = f2b(acc[k2 + 3]);
      *(ushort4*)&dst[k2] = o;
    }
    if (kcB == 0 && tid < 64) {
      const float* bb = z ? bk : bq;
      float a2 = 0.f;
      for (int d = 0; d < 64; ++d) a2 += bb[h * 64 + d] * Pl[d * 64 + tid];
      biasC[z * 768 + h * 64 + tid] = a2;
    }
    return;
  }
  // ---- Wv / Wo tile transpose
  const int isWo = bid >= 25968;
  int v = bid - (isWo ? 25968 : 25824);
  int kb = v / 12, rb = v - kb * 12;
  const float* W = isWo ? Wo : Wv;
  float (*T)[68] = (float(*)[68])sm;               // 64*68 floats = 17 KB
#pragma unroll
  for (int p = 0; p < 4; ++p) {
    int idx = tid + p * 256;                       // 1024 float4s
    int rr = idx >> 4, c4 = (idx & 15) * 4;
    float4 x = *(const float4*)&W[(size_t)(kb * 64 + rr) * H_ + rb * 64 + c4];
    T[rr][c4] = x.x; T[rr][c4 + 1] = x.y; T[rr][c4 + 2] = x.z; T[rr][c4 + 3] = x.w;
  }
  __syncthreads();
  U16* dst = isWo ? WoTH : WcatH;
  const int rbase = (isWo ? 0 : 1536) + rb * 64;
#pragma unroll
  for (int p = 0; p < 4; ++p) {
    int idx = tid + p * 256;
    int r2 = idx >> 4, c2 = (idx & 15) * 4;
    ushort4 o;
    o.x = f2b(T[c2 + 0][r2]); o.y = f2b(T[c2 + 1][r2]);
    o.z = f2b(T[c2 + 2][r2]); o.w = f2b(T[c2 + 3][r2]);
    *(ushort4*)&dst[(size_t)(rbase + r2) * H_ + kb * 64 + c2] = o;
  }
  if (!isWo && kb == 0 && rb == 0) {               // bv -> biasC[1536..2304)
#pragma unroll
    for (int p = 0; p < 3; ++p) biasC[1536 + tid + p * 256] = bv[tid + p * 256];
  }
}

// ---------- K2: persistent 128x128 bf16 GEMM + fused maxexp epilogue ----------
// 512 blocks (2/CU), 256 threads (4 waves, 2x2), BK=64, dbuf 32 KB LDS.
// Block b: mt = b&255 fixed, nt = (b>>8) + 2*jj, jj=0..8. Counted vmcnt(8).
__global__ __launch_bounds__(256, 2) void gemm_qkv(
    const U16* __restrict__ Ahi, const U16* __restrict__ Bhi,
    const float* __restrict__ bias,
    U16* __restrict__ qp, U16* __restrict__ kpT, U16* __restrict__ vT) {
  __shared__ __align__(16) U16 Us[32768];            // [buf][A/B][128][64] bf16
  const int tid = threadIdx.x, w = tid >> 6, lane = tid & 63;
  const int quad = lane >> 4, l16 = lane & 15;
  const int b = blockIdx.x;                          // 512 persistent blocks
  const int mt = b & 255, nt0 = b >> 8;
  const int rowA0 = mt * 128;
  const int wm = w & 1, wn = w >> 1;
  const U16* srcA[4];
  int rowBl[4];
  unsigned ldsc[4];
  const int kch = ((lane & 7) ^ (lane >> 3)) * 8;    // pre-swizzled src chunk
#pragma unroll
  for (int t = 0; t < 4; ++t) {
    int c = w * 4 + t;
    int row = c * 8 + (lane >> 3);
    srcA[t] = Ahi + (size_t)(rowA0 + row) * H_ + kch;
    rowBl[t] = row;
    ldsc[t] = (unsigned)c * 512;
  }
  auto stage = [&](int jn, int tn, int bi) {
    const int colB = (nt0 + 2 * jn) * 128;
    unsigned ub = (unsigned)bi * 16384u;
#pragma unroll
    for (int t = 0; t < 4; ++t) {
      gl2lds16(srcA[t] + tn * 64, &Us[ub + ldsc[t]]);
      gl2lds16(Bhi + (size_t)(colB + rowBl[t]) * H_ + tn * 64 + kch,
               &Us[ub + 8192u + ldsc[t]]);
    }
  };

  stage(0, 0, 0);
  for (int jj = 0; jj < 9; ++jj) {
    const int colB0 = (nt0 + 2 * jj) * 128;
    f32x4 acc[4][4] = {};
    for (int t = 0; t < 12; ++t) {
      const bool more = !(jj == 8 && t == 11);
      if (more) {
        if (t < 11) stage(jj, t + 1, (t + 1) & 1);
        else        stage(jj + 1, 0, 0);
        asm volatile("s_waitcnt vmcnt(8)" ::: "memory");
      } else {
        asm volatile("s_waitcnt vmcnt(0)" ::: "memory");
      }
      __builtin_amdgcn_sched_barrier(0);
      __builtin_amdgcn_s_barrier();
      __builtin_amdgcn_sched_barrier(0);
      const unsigned ab = (unsigned)(t & 1) * 16384u;
      bf16x8 ah[4][2], bh[4][2];
#pragma unroll
      for (int i = 0; i < 4; ++i)
#pragma unroll
        for (int ks = 0; ks < 2; ++ks)
          ah[i][ks] = *(const bf16x8*)&Us[ab +
              (unsigned)((wm * 64 + i * 16 + l16) * 64 +
                         (((ks * 4 + quad) ^ (l16 & 7)) * 8))];
#pragma unroll
      for (int j = 0; j < 4; ++j)
#pragma unroll
        for (int ks = 0; ks < 2; ++ks)
          bh[j][ks] = *(const bf16x8*)&Us[ab + 8192u +
              (unsigned)((wn * 64 + j * 16 + l16) * 64 +
                         (((ks * 4 + quad) ^ (l16 & 7)) * 8))];
      asm volatile("s_waitcnt lgkmcnt(0)" ::: "memory");
      __builtin_amdgcn_sched_barrier(0);
      __builtin_amdgcn_s_setprio(1);
#pragma unroll
      for (int ks = 0; ks < 2; ++ks)
#pragma unroll
        for (int j = 0; j < 4; ++j)
#pragma unroll
          for (int i = 0; i < 4; ++i)
            acc[i][j] = __builtin_amdgcn_mfma_f32_16x16x32_bf16(
                ah[i][ks], bh[j][ks], acc[i][j], 0, 0, 0);
      __builtin_amdgcn_s_setprio(0);
      __builtin_amdgcn_sched_barrier(0);
      __builtin_amdgcn_s_barrier();
      __builtin_amdgcn_sched_barrier(0);
    }
    // ---- epilogue for this tile (no LDS use; overlaps next stage)
    const int col64 = colB0 + wn * 64;
    float bj[4];
#pragma unroll
    for (int j = 0; j < 4; ++j) bj[j] = bias[col64 + j * 16 + l16];
    if (col64 < 768) {                            // q logits -> row-major qp
      const int h = col64 >> 6;
#pragma unroll
      for (int i = 0; i < 4; ++i) {
#pragma unroll
        for (int r = 0; r < 4; ++r) {
          int row = rowA0 + wm * 64 + i * 16 + quad * 4 + r;
          float v0 = acc[i][0][r] + bj[0], v1 = acc[i][1][r] + bj[1];
          float v2 = acc[i][2][r] + bj[2], v3 = acc[i][3][r] + bj[3];
          float mx = fmaxf(fmaxf(v0, v1), fmaxf(v2, v3));
          mx = fmaxf(mx, __shfl_xor(mx, 1));
          mx = fmaxf(mx, __shfl_xor(mx, 2));
          mx = fmaxf(mx, __shfl_xor(mx, 4));
          mx = fmaxf(mx, __shfl_xor(mx, 8));
          int bb = row >> 13, s = row & 8191;
          size_t base = ((size_t)(bb * NH_ + h) * S_ + s) * 64 + l16;
          qp[base +  0] = f2b(__expf(v0 - mx));
          qp[base + 16] = f2b(__expf(v1 - mx));
          qp[base + 32] = f2b(__expf(v2 - mx));
          qp[base + 48] = f2b(__expf(v3 - mx));
        }
      }
    } else {                                      // k (exp) or v -> transposed
      const int isv = col64 >= 1536;
      const int h = (col64 - (isv ? 1536 : 768)) >> 6;
      U16* dstT = isv ? vT : kpT;
      const int bh2 = (rowA0 >> 13) * NH_ + h;
#pragma unroll
      for (int i = 0; i < 4; ++i) {
        float er[4][4];                           // [j][r]
#pragma unroll
        for (int r = 0; r < 4; ++r) {
          float v0 = acc[i][0][r] + bj[0], v1 = acc[i][1][r] + bj[1];
          float v2 = acc[i][2][r] + bj[2], v3 = acc[i][3][r] + bj[3];
          if (!isv) {
            float mx = fmaxf(fmaxf(v0, v1), fmaxf(v2, v3));
            mx = fmaxf(mx, __shfl_xor(mx, 1));
            mx = fmaxf(mx, __shfl_xor(mx, 2));
            mx = fmaxf(mx, __shfl_xor(mx, 4));
            mx = fmaxf(mx, __shfl_xor(mx, 8));
            v0 = __expf(v0 - mx); v1 = __expf(v1 - mx);
            v2 = __expf(v2 - mx); v3 = __expf(v3 - mx);
          }
          er[0][r] = v0; er[1][r] = v1; er[2][r] = v2; er[3][r] = v3;
        }
        int n = rowA0 + wm * 64 + i * 16 + quad * 4;   // 4-aligned
        int s = n & 8191;
#pragma unroll
        for (int j = 0; j < 4; ++j) {
          ushort4 o;
          o.x = f2b(er[j][0]); o.y = f2b(er[j][1]);
          o.z = f2b(er[j][2]); o.w = f2b(er[j][3]);
          *(ushort4*)&dstT[((size_t)bh2 * 64 + j * 16 + l16) * S_ + s] = o;
        }
      }
    }
  }
}

// ---------- K3: kv summary via MFMA: kvT[bh][d][m], row 64 = ksum ----------
__global__ __launch_bounds__(256, 4) void kv_accum_mfma(
    const U16* __restrict__ kpT, const U16* __restrict__ vT,
    float* __restrict__ kvT) {
  __shared__ __align__(16) U16 Us[2 * 64 * 64];   // [0:4096]=vT tile, [4096:8192]=kpT
  const int tid = threadIdx.x, w = tid >> 6, lane = tid & 63;
  const int quad = lane >> 4, l16 = lane & 15;
  const int bh = blockIdx.y;
  const int n0 = blockIdx.x * 512;
  const U16* srcs[4];
  unsigned ldsoff[4];
#pragma unroll
  for (int t = 0; t < 4; ++t) {
    int c = w * 4 + t, buf = c >> 3;              // 0..15; buf 0 = vT, 1 = kpT
    int r = (c & 7) * 8 + (lane >> 3);
    const U16* base = buf ? kpT : vT;
    srcs[t] = base + ((size_t)bh * 64 + r) * S_ + n0 + (lane & 7) * 8;
    ldsoff[t] = buf * 4096 + (c & 7) * 512;
  }
  f32x4 acc[4] = {};
  float ks[4] = {0.f, 0.f, 0.f, 0.f};
  for (int nc = 0; nc < 512; nc += 64) {
#pragma unroll
    for (int t = 0; t < 4; ++t) gl2lds16(srcs[t] + nc, &Us[ldsoff[t]]);
    __syncthreads();
#pragma unroll
    for (int k0 = 0; k0 < 64; k0 += 32) {
      bf16x8 av = *(const bf16x8*)&Us[(w * 16 + l16) * 64 + k0 + quad * 8];
#pragma unroll
      for (int j = 0; j < 4; ++j) {
        bf16x8 bk = *(const bf16x8*)&Us[4096 + (j * 16 + l16) * 64 + k0 + quad * 8];
        if (w == 0) {
#pragma unroll
          for (int e = 0; e < 8; ++e) ks[j] += b2f((U16)bk[e]);
        }
        acc[j] = __builtin_amdgcn_mfma_f32_16x16x32_bf16(av, bk, acc[j], 0, 0, 0);
      }
    }
    __syncthreads();
  }
#pragma unroll
  for (int j = 0; j < 4; ++j)
#pragma unroll
    for (int r = 0; r < 4; ++r) {
      int d = w * 16 + quad * 4 + r;
      atomicAdd(&kvT[((size_t)bh * 80 + d) * 64 + j * 16 + l16], acc[j][r]);
    }
  if (w == 0) {
#pragma unroll
    for (int j = 0; j < 4; ++j) {
      ks[j] += __shfl_xor(ks[j], 16);
      ks[j] += __shfl_xor(ks[j], 32);
    }
    if (lane < 16) {
#pragma unroll
      for (int j = 0; j < 4; ++j)
        atomicAdd(&kvT[((size_t)bh * 80 + 64) * 64 + j * 16 + lane], ks[j]);
    }
  }
}

// ---------- K4: ctx = (qp @ kv)/(norm+eps); norm = MFMA tile j=4 ----------
__global__ __launch_bounds__(256) void ctx_gemm_k(
    const U16* __restrict__ qp, const float* __restrict__ kvT,
    U16* __restrict__ ctx) {
  __shared__ __align__(16) U16 As[128 * 64];
  __shared__ __align__(16) U16 Bs[80 * 64];
  int bh = blockIdx.y, row0 = blockIdx.x * 128;
  int tid = threadIdx.x, w = tid >> 6, lane = tid & 63;
  int quad = lane >> 4, l16 = lane & 15;
  const U16* Ab = qp + ((size_t)bh * S_ + row0) * 64;
#pragma unroll
  for (int t = 0; t < 4; ++t) {
    int cb = (w * 4 + t) * 64;
    gl2lds16(Ab + (size_t)(cb + lane) * 8, &As[cb * 8]);
  }
  const float4* kv4 = (const float4*)(kvT + (size_t)bh * 5120);
#pragma unroll
  for (int t = 0; t < 5; ++t) {
    int idx = t * 256 + tid;          // 1280 float4s = 80*64 floats
    float4 f = kv4[idx];
    ushort4 o;
    o.x = f2b(f.x); o.y = f2b(f.y); o.z = f2b(f.z); o.w = f2b(f.w);
    *(ushort4*)&Bs[idx * 4] = o;
  }
  __syncthreads();
  f32x4 acc[2][5] = {};
#pragma unroll
  for (int k0 = 0; k0 < 64; k0 += 32) {
    bf16x8 a[2], fb[5];
#pragma unroll
    for (int i = 0; i < 2; ++i)
      a[i] = *(const bf16x8*)&As[(w * 32 + i * 16 + l16) * 64 + k0 + quad * 8];
#pragma unroll
    for (int j = 0; j < 5; ++j)
      fb[j] = *(const bf16x8*)&Bs[(j * 16 + l16) * 64 + k0 + quad * 8];
#pragma unroll
    for (int j = 0; j < 5; ++j)
#pragma unroll
      for (int i = 0; i < 2; ++i)
        acc[i][j] = __builtin_amdgcn_mfma_f32_16x16x32_bf16(a[i], fb[j], acc[i][j], 0, 0, 0);
  }
  int b = bh / NH_, h = bh - b * NH_;
#pragma unroll
  for (int i = 0; i < 2; ++i) {
#pragma unroll
    for (int r = 0; r < 4; ++r) {
      int s = row0 + w * 32 + i * 16 + quad * 4 + r;
      float nv = __shfl(acc[i][4][r], lane & 48);   // col 64 (l16==0) = norm(row)
      float inv = 1.f / (nv + EPS_);
      size_t base = ((size_t)b * S_ + s) * H_ + h * 64;
#pragma unroll
      for (int j = 0; j < 4; ++j)
        ctx[base + j * 16 + l16] = f2b(acc[i][j][r] * inv);
    }
  }
}

// ---------- K5: out = ctx @ WoT^T + bo (persistent 128x128, BK=64) ----------
// Clone of gemm_qkv's loop. 512 blocks (2/CU): mt = b&255, nt0 = b>>8,
// jj=0..2, nt = nt0 + 2*jj (covers all 6 col tiles of 768).
__global__ __launch_bounds__(256, 2) void out_gemm(
    const U16* __restrict__ Ahi, const U16* __restrict__ Bhi,
    const float* __restrict__ bias, float* __restrict__ C) {
  __shared__ __align__(16) U16 Us[32768];
  const int tid = threadIdx.x, w = tid >> 6, lane = tid & 63;
  const int quad = lane >> 4, l16 = lane & 15;
  const int b = blockIdx.x;                          // 512 persistent blocks
  const int mt = b & 255, nt0 = b >> 8;
  const int rowA0 = mt * 128;
  const int wm = w & 1, wn = w >> 1;
  const U16* srcA[4];
  int rowBl[4];
  unsigned ldsc[4];
  const int kch = ((lane & 7) ^ (lane >> 3)) * 8;
#pragma unroll
  for (int t = 0; t < 4; ++t) {
    int c = w * 4 + t;
    int row = c * 8 + (lane >> 3);
    srcA[t] = Ahi + (size_t)(rowA0 + row) * H_ + kch;
    rowBl[t] = row;
    ldsc[t] = (unsigned)c * 512;
  }
  auto stage = [&](int jn, int tn, int bi) {
    const int colB = (nt0 + 2 * jn) * 128;
    unsigned ub = (unsigned)bi * 16384u;
#pragma unroll
    for (int t = 0; t < 4; ++t) {
      gl2lds16(srcA[t] + tn * 64, &Us[ub + ldsc[t]]);
      gl2lds16(Bhi + (size_t)(colB + rowBl[t]) * H_ + tn * 64 + kch,
               &Us[ub + 8192u + ldsc[t]]);
    }
  };

  stage(0, 0, 0);
  for (int jj = 0; jj < 3; ++jj) {
    const int colB0 = (nt0 + 2 * jj) * 128;
    f32x4 acc[4][4] = {};
    for (int t = 0; t < 12; ++t) {
      const bool more = !(jj == 2 && t == 11);
      if (more) {
        if (t < 11) stage(jj, t + 1, (t + 1) & 1);
        else        stage(jj + 1, 0, 0);
        asm volatile("s_waitcnt vmcnt(8)" ::: "memory");
      } else {
        asm volatile("s_waitcnt vmcnt(0)" ::: "memory");
      }
      __builtin_amdgcn_sched_barrier(0);
      __builtin_amdgcn_s_barrier();
      __builtin_amdgcn_sched_barrier(0);
      const unsigned ab = (unsigned)(t & 1) * 16384u;
      bf16x8 ah[4][2], bh[4][2];
#pragma unroll
      for (int i = 0; i < 4; ++i)
#pragma unroll
        for (int ks = 0; ks < 2; ++ks)
          ah[i][ks] = *(const bf16x8*)&Us[ab +
              (unsigned)((wm * 64 + i * 16 + l16) * 64 +
                         (((ks * 4 + quad) ^ (l16 & 7)) * 8))];
#pragma unroll
      for (int j = 0; j < 4; ++j)
#pragma unroll
        for (int ks = 0; ks < 2; ++ks)
          bh[j][ks] = *(const bf16x8*)&Us[ab + 8192u +
              (unsigned)((wn * 64 + j * 16 + l16) * 64 +
                         (((ks * 4 + quad) ^ (l16 & 7)) * 8))];
      asm volatile("s_waitcnt lgkmcnt(0)" ::: "memory");
      __builtin_amdgcn_sched_barrier(0);
      __builtin_amdgcn_s_setprio(1);
#pragma unroll
      for (int ks = 0; ks < 2; ++ks)
#pragma unroll
        for (int j = 0; j < 4; ++j)
#pragma unroll
          for (int i = 0; i < 4; ++i)
            acc[i][j] = __builtin_amdgcn_mfma_f32_16x16x32_bf16(
                ah[i][ks], bh[j][ks], acc[i][j], 0, 0, 0);
      __builtin_amdgcn_s_setprio(0);
      __builtin_amdgcn_sched_barrier(0);
      __builtin_amdgcn_s_barrier();
      __builtin_amdgcn_sched_barrier(0);
    }
    // ---- epilogue (no LDS use; overlaps next stage)
#pragma unroll
    for (int i = 0; i < 4; ++i) {
      int row = rowA0 + wm * 64 + i * 16 + quad * 4;
#pragma unroll
      for (int j = 0; j < 4; ++j) {
        int col = colB0 + wn * 64 + j * 16 + l16;
        float bvv = bias[col];
#pragma unroll
        for (int r = 0; r < 4; ++r)
          C[(size_t)(row + r) * H_ + col] = acc[i][j][r] + bvv;
      }
    }
  }
}

extern "C" void kernel_launch(void* const* d_in, const int* in_sizes, int n_in,
                              void* d_out, int out_size, void* d_ws, size_t ws_size,
                              hipStream_t stream) {
  const float* hs = (const float*)d_in[0];
  const float* Wq = (const float*)d_in[1];
  const float* bq = (const float*)d_in[2];
  const float* Wk = (const float*)d_in[3];
  const float* bk = (const float*)d_in[4];
  const float* Wv = (const float*)d_in[5];
  const float* bv = (const float*)d_in[6];
  const float* Wo = (const float*)d_in[7];
  const float* bo = (const float*)d_in[8];
  const float* P  = (const float*)d_in[9];
  float* out = (float*)d_out;

  char* ws = (char*)d_ws;
  size_t off = 0;
  auto alloc = [&](size_t bytes) -> void* {
    void* p = ws + off;
    off = (off + bytes + 255) & ~(size_t)255;
    return p;
  };
  U16*   hs_hi = (U16*)alloc(50331648);     // [32768,768] bf16 (reused as ctx)
  U16*   WcatH = (U16*)alloc(3538944);      // [2304,768] bf16 (B^T layout)
  U16*   WoTH  = (U16*)alloc(1179648);      // [768,768] bf16 (Wo^T)
  float* biasC = (float*)alloc(9216);
  U16*   qp    = (U16*)alloc(50331648);     // [48,8192,64] bf16 row-major
  U16*   kpT   = (U16*)alloc(50331648);     // [48,64,8192] bf16 transposed
  U16*   vT    = (U16*)alloc(50331648);     // [48,64,8192] bf16 transposed
  float* kvT   = (float*)alloc(983040);     // [48,80,64] fp32 (row 64 = ksum)
  U16*   ctx   = hs_hi;                     // hs dead after QKV GEMM: reuse

  prologue<<<dim3(26112), dim3(256), 0, stream>>>(
      hs, Wq, bq, Wk, bk, Wv, bv, Wo, P, hs_hi, WcatH, WoTH, biasC, kvT);
  gemm_qkv<<<dim3(512), dim3(256), 0, stream>>>(hs_hi, WcatH, biasC, qp, kpT, vT);
  kv_accum_mfma<<<dim3(16, 48), dim3(256), 0, stream>>>(kpT, vT, kvT);
  ctx_gemm_k<<<dim3(64, 48), dim3(256), 0, stream>>>(qp, kvT, ctx);
  out_gemm<<<dim3(512), dim3(256), 0, stream>>>(ctx, WoTH, bo, out);
}